// Round 10
// baseline (355.695 us; speedup 1.0000x reference)
//
#include <hip/hip_runtime.h>

typedef unsigned short u16;
typedef __attribute__((ext_vector_type(8))) short bf16x8;
typedef __attribute__((ext_vector_type(4))) float f32x4;

#define B_SZ   2
#define L_SZ   2048
#define DM     1024
#define DI     2048
#define NST    16
#define RNK    64
#define TOK    (B_SZ * L_SZ)   // 4096
#define NC     128             // scan chunks (8 blocks/CU)
#define CLEN   (L_SZ / NC)     // 16 steps per chunk
#define XDS    128             // x_dbl row stride (padded from 96)
#define KSPL   8               // K-split for xdbl gemm

__device__ __forceinline__ float bf2f(u16 u) {
    return __uint_as_float(((unsigned int)u) << 16);
}
__device__ __forceinline__ u16 f2bf(float f) {
    unsigned int x = __float_as_uint(f);
    x += 0x7fffu + ((x >> 16) & 1u);   // RNE
    return (u16)(x >> 16);
}
__device__ __forceinline__ float silu(float v) {
    return v / (1.f + __expf(-v));
}
__device__ __forceinline__ float softplus_f(float v) {
    return (v > 20.f) ? v : log1pf(__expf(v));
}
// 16-byte async global->LDS (gfx950). LDS dest = wave-uniform base + lane*16.
__device__ __forceinline__ void gload16(const u16* g, u16* l) {
    __builtin_amdgcn_global_load_lds(
        (const __attribute__((address_space(1))) void*)g,
        (__attribute__((address_space(3))) void*)l, 16, 0, 0);
}
__device__ __forceinline__ ushort4 cvt4(const float4 v) {
    ushort4 o;
    o.x = f2bf(v.x); o.y = f2bf(v.y); o.z = f2bf(v.z); o.w = f2bf(v.w);
    return o;
}

// ---------------------------------------------------------------------------
// Fused f32 -> bf16 conversion of all 5 GEMM operands (one launch).
// ---------------------------------------------------------------------------
#define Q_XB   1048576                    // TOK*DM/4
#define Q_WIN  (Q_XB + 1048576)           // + 2*DI*DM/4
#define Q_WOUT (Q_WIN + 524288)           // + DM*DI/4
#define Q_WX   (Q_WOUT + 65536)           // + XDS*DI/4 (padded)
#define Q_WDT  (Q_WX + 32768)             // + DI*RNK/4
__global__ __launch_bounds__(256)
void cvt_all(const float4* __restrict__ x,  const float4* __restrict__ Wi,
             const float4* __restrict__ Wo, const float4* __restrict__ Wx,
             const float4* __restrict__ Wd,
             ushort4* __restrict__ xb,  ushort4* __restrict__ Wib,
             ushort4* __restrict__ Wob, ushort4* __restrict__ Wxb,
             ushort4* __restrict__ Wdb)
{
    const int i = blockIdx.x * 256 + threadIdx.x;
    if (i < Q_XB) {
        xb[i] = cvt4(x[i]);
    } else if (i < Q_WIN) {
        const int j = i - Q_XB;  Wib[j] = cvt4(Wi[j]);
    } else if (i < Q_WOUT) {
        const int j = i - Q_WIN; Wob[j] = cvt4(Wo[j]);
    } else if (i < Q_WX) {
        const int j = i - Q_WOUT;
        const int row = (j * 4) >> 11;
        if (row < 96) Wxb[j] = cvt4(Wx[j]);
        else          Wxb[j] = (ushort4){0, 0, 0, 0};
    } else if (i < Q_WDT) {
        const int j = i - Q_WX;  Wdb[j] = cvt4(Wd[j]);
    }
}

// ---------------------------------------------------------------------------
// GEMM  C[M][N] = A[M][K] @ B[N][K]^T  (swapped-MFMA epilogue, gload16 staging)
// EPI==0: float4 -> outF ; EPI==1: in_proj split ; EPI==2: softplus+bias -> bf16
// ---------------------------------------------------------------------------
template<int EPI>
__global__ __launch_bounds__(256, 2)
void gemm_bt(const u16* __restrict__ A, const u16* __restrict__ B,
             const int K, const int N,
             u16* __restrict__ out0, u16* __restrict__ out1,
             float* __restrict__ outF, const float* __restrict__ bias)
{
    __shared__ u16 sA[128 * 32];
    __shared__ u16 sB[128 * 32];

    const int tid  = threadIdx.x;
    const int rowBase = blockIdx.x << 7;
    const int colBase = blockIdx.y << 7;
    const int wave = tid >> 6, lane = tid & 63;
    const int wm = (wave >> 1) << 6;
    const int wn = (wave & 1) << 6;
    const int lrow = lane & 15, quad = lane >> 4;

    const int sr  = tid >> 2;
    const int skc = tid & 3;
    const u16* Ap = A + (size_t)(rowBase + sr) * K + skc * 8;
    const u16* Bp = B + (size_t)(colBase + sr) * K + skc * 8;
    const size_t rowJump = (size_t)64 * K;
    u16* lA0 = &sA[tid * 8];
    u16* lA1 = &sA[64 * 32 + tid * 8];
    u16* lB0 = &sB[tid * 8];
    u16* lB1 = &sB[64 * 32 + tid * 8];

    f32x4 acc[4][4];
#pragma unroll
    for (int i = 0; i < 4; ++i)
#pragma unroll
        for (int j = 0; j < 4; ++j) acc[i][j] = (f32x4){0.f, 0.f, 0.f, 0.f};

    const int KT = K >> 5;
    for (int kt = 0; kt < KT; ++kt) {
        const int ko = kt * 32;
        gload16(Ap + ko, lA0);
        gload16(Ap + ko + rowJump, lA1);
        gload16(Bp + ko, lB0);
        gload16(Bp + ko + rowJump, lB1);
        __syncthreads();

        bf16x8 af[4], bfr[4];
#pragma unroll
        for (int i = 0; i < 4; ++i)
            af[i] = *(const bf16x8*)&sA[(wm + i * 16 + lrow) * 32 + quad * 8];
#pragma unroll
        for (int j = 0; j < 4; ++j)
            bfr[j] = *(const bf16x8*)&sB[(wn + j * 16 + lrow) * 32 + quad * 8];

#pragma unroll
        for (int i = 0; i < 4; ++i)
#pragma unroll
            for (int j = 0; j < 4; ++j)
                acc[i][j] = __builtin_amdgcn_mfma_f32_16x16x32_bf16(
                    bfr[j], af[i], acc[i][j], 0, 0, 0);   // swapped: C^T frags
        __syncthreads();
    }

#pragma unroll
    for (int i = 0; i < 4; ++i) {
        const int token = rowBase + wm + i * 16 + lrow;
#pragma unroll
        for (int j = 0; j < 4; ++j) {
            const int ch = colBase + wn + j * 16 + quad * 4;
            const f32x4 v = acc[i][j];
            if (EPI == 0) {
                *(float4*)&outF[(size_t)token * N + ch] =
                    (float4){v[0], v[1], v[2], v[3]};
            } else if (EPI == 2) {
                const float4 bb = *(const float4*)&bias[ch];
                ushort4 o;
                o.x = f2bf(softplus_f(v[0] + bb.x));
                o.y = f2bf(softplus_f(v[1] + bb.y));
                o.z = f2bf(softplus_f(v[2] + bb.z));
                o.w = f2bf(softplus_f(v[3] + bb.w));
                *(ushort4*)&out0[(size_t)token * N + ch] = o;
            } else {
                if (ch < DI) {
                    ushort4 o;
                    o.x = f2bf(v[0]); o.y = f2bf(v[1]);
                    o.z = f2bf(v[2]); o.w = f2bf(v[3]);
                    *(ushort4*)&out0[(size_t)token * DI + ch] = o;
                } else {
                    ushort4 o;
                    o.x = f2bf(silu(v[0])); o.y = f2bf(silu(v[1]));
                    o.z = f2bf(silu(v[2])); o.w = f2bf(silu(v[3]));
                    *(ushort4*)&out1[(size_t)token * DI + (ch - DI)] = o;
                }
            }
        }
    }
}

// ---------------------------------------------------------------------------
// xdbl GEMM: part[ks][128 tokens][128] = xc_tile @ WxP^T over K-slice ks*256.
// ---------------------------------------------------------------------------
__global__ __launch_bounds__(256, 2)
void gemm_xdbl(const u16* __restrict__ A, const u16* __restrict__ B,
               float* __restrict__ part)
{
    __shared__ u16 sA[128 * 32];
    __shared__ u16 sB[128 * 32];

    const int tid  = threadIdx.x;
    const int rowBase = blockIdx.x << 7;
    const int ks   = blockIdx.y;
    const int k0   = ks * (DI / KSPL);
    const int wave = tid >> 6, lane = tid & 63;
    const int wm = (wave >> 1) << 6;
    const int wn = (wave & 1) << 6;
    const int lrow = lane & 15, quad = lane >> 4;

    const int sr  = tid >> 2;
    const int skc = tid & 3;
    const u16* Ap = A + (size_t)(rowBase + sr) * DI + k0 + skc * 8;
    const u16* Bp = B + (size_t)sr * DI + k0 + skc * 8;
    const size_t rowJump = (size_t)64 * DI;
    u16* lA0 = &sA[tid * 8];
    u16* lA1 = &sA[64 * 32 + tid * 8];
    u16* lB0 = &sB[tid * 8];
    u16* lB1 = &sB[64 * 32 + tid * 8];

    f32x4 acc[4][4];
#pragma unroll
    for (int i = 0; i < 4; ++i)
#pragma unroll
        for (int j = 0; j < 4; ++j) acc[i][j] = (f32x4){0.f, 0.f, 0.f, 0.f};

    const int KT = (DI / KSPL) >> 5;            // 8
    for (int kt = 0; kt < KT; ++kt) {
        const int ko = kt * 32;
        gload16(Ap + ko, lA0);
        gload16(Ap + ko + rowJump, lA1);
        gload16(Bp + ko, lB0);
        gload16(Bp + ko + rowJump, lB1);
        __syncthreads();

        bf16x8 af[4], bfr[4];
#pragma unroll
        for (int i = 0; i < 4; ++i)
            af[i] = *(const bf16x8*)&sA[(wm + i * 16 + lrow) * 32 + quad * 8];
#pragma unroll
        for (int j = 0; j < 4; ++j)
            bfr[j] = *(const bf16x8*)&sB[(wn + j * 16 + lrow) * 32 + quad * 8];

#pragma unroll
        for (int i = 0; i < 4; ++i)
#pragma unroll
            for (int j = 0; j < 4; ++j)
                acc[i][j] = __builtin_amdgcn_mfma_f32_16x16x32_bf16(
                    bfr[j], af[i], acc[i][j], 0, 0, 0);
        __syncthreads();
    }

    float* base = part + (size_t)ks * TOK * XDS;
#pragma unroll
    for (int i = 0; i < 4; ++i) {
        const int token = rowBase + wm + i * 16 + lrow;
#pragma unroll
        for (int j = 0; j < 4; ++j) {
            const int ch = wn + j * 16 + quad * 4;
            const f32x4 v = acc[i][j];
            *(float4*)&base[(size_t)token * XDS + ch] =
                (float4){v[0], v[1], v[2], v[3]};
        }
    }
}

// sum the 8 K-slice partials -> xdblP [TOK x 128] f32; also emit dltB
__global__ __launch_bounds__(256)
void reduce_part(const float4* __restrict__ part, float4* __restrict__ xdbl,
                 u16* __restrict__ dltB)
{
    const int i = blockIdx.x * 256 + threadIdx.x;   // [0, TOK*XDS/4)
    const int n4 = TOK * XDS / 4;
    float4 s = part[i];
#pragma unroll
    for (int ks = 1; ks < KSPL; ++ks) {
        const float4 v = part[(size_t)ks * n4 + i];
        s.x += v.x; s.y += v.y; s.z += v.z; s.w += v.w;
    }
    xdbl[i] = s;
    const int col4 = (i & (XDS / 4 - 1)) * 4;
    if (col4 < RNK) {
        const int row = i >> 5;                      // XDS/4 = 32
        *(ushort4*)(dltB + (size_t)row * RNK + col4) = cvt4(s);
    }
}

// ---------------------------------------------------------------------------
// causal depthwise conv (K=4) + silu — vectorized x4 channels/thread
// ---------------------------------------------------------------------------
__global__ __launch_bounds__(256)
void conv_silu_kernel(const u16* __restrict__ xm, const float* __restrict__ cw,
                      const float* __restrict__ cb, u16* __restrict__ xc)
{
    const int idx = blockIdx.x * 256 + threadIdx.x;   // [0, TOK*DI/4)
    const int ch  = (idx & (DI / 4 - 1)) * 4;
    const int t   = idx >> 9;                          // DI/4 = 512
    const int l   = t & (L_SZ - 1);

    const float4 w0 = ((const float4*)cw)[ch];        // weights for ch..ch+3
    const float4 w1 = ((const float4*)cw)[ch + 1];
    const float4 w2 = ((const float4*)cw)[ch + 2];
    const float4 w3 = ((const float4*)cw)[ch + 3];
    const float4 bb = *(const float4*)(cb + ch);
    float a0 = bb.x, a1 = bb.y, a2 = bb.z, a3 = bb.w;

    const u16* base = xm + (size_t)t * DI + ch;
    if (l >= 3) {
        const ushort4 v = *(const ushort4*)(base - 3 * DI);
        a0 += w0.x * bf2f(v.x); a1 += w1.x * bf2f(v.y);
        a2 += w2.x * bf2f(v.z); a3 += w3.x * bf2f(v.w);
    }
    if (l >= 2) {
        const ushort4 v = *(const ushort4*)(base - 2 * DI);
        a0 += w0.y * bf2f(v.x); a1 += w1.y * bf2f(v.y);
        a2 += w2.y * bf2f(v.z); a3 += w3.y * bf2f(v.w);
    }
    if (l >= 1) {
        const ushort4 v = *(const ushort4*)(base - DI);
        a0 += w0.z * bf2f(v.x); a1 += w1.z * bf2f(v.y);
        a2 += w2.z * bf2f(v.z); a3 += w3.z * bf2f(v.w);
    }
    {
        const ushort4 v = *(const ushort4*)(base);
        a0 += w0.w * bf2f(v.x); a1 += w1.w * bf2f(v.y);
        a2 += w2.w * bf2f(v.z); a3 += w3.w * bf2f(v.w);
    }
    ushort4 o;
    o.x = f2bf(silu(a0)); o.y = f2bf(silu(a1));
    o.z = f2bf(silu(a2)); o.w = f2bf(silu(a3));
    *(ushort4*)(xc + (size_t)t * DI + ch) = o;
}

// ---------------------------------------------------------------------------
// Chunked selective scan (NC=128, CLEN=16). thread = channel; states in regs.
// Pointer-bump addressing; unconditional next-row prefetch (lands in the next
// workspace buffer on the final row — mapped, value discarded).
// ---------------------------------------------------------------------------
__global__ __launch_bounds__(256)
void scan_pass1(const u16* __restrict__ dlt16, const float* __restrict__ xdbl,
                const u16* __restrict__ xc, const float* __restrict__ A_log,
                u16* __restrict__ hfin, float* __restrict__ Ssum)
{
    const int tid = threadIdx.x;
    const int ch  = blockIdx.x * 256 + tid;
    const int b   = blockIdx.y / NC;
    const int c   = blockIdx.y % NC;
    const int t0  = b * L_SZ + c * CLEN;

    __shared__ float sB[CLEN][16];
    {   // CLEN*16 == 256
        const int i = tid >> 4, nn = tid & 15;
        sB[i][nn] = xdbl[(size_t)(t0 + i) * XDS + 64 + nn];
    }

    float A[16];
    {
        const float4* Ar = (const float4*)(A_log + (size_t)ch * 16);
#pragma unroll
        for (int k = 0; k < 4; ++k) {
            const float4 v = Ar[k];
            A[4*k+0] = -__expf(v.x); A[4*k+1] = -__expf(v.y);
            A[4*k+2] = -__expf(v.z); A[4*k+3] = -__expf(v.w);
        }
    }
    __syncthreads();

    float h[16];
#pragma unroll
    for (int n = 0; n < 16; ++n) h[n] = 0.f;
    float S = 0.f;

    const u16* dp  = dlt16 + (size_t)t0 * DI + ch;
    const u16* xcp = xc    + (size_t)t0 * DI + ch;
    float d  = bf2f(*dp);
    float xv = bf2f(*xcp);

    for (int i = 0; i < CLEN; ++i) {
        const float dn = bf2f(dp[DI]);     // unconditional prefetch
        const float xn = bf2f(xcp[DI]);
        const float dx = d * xv;
        S += d;
#pragma unroll
        for (int k = 0; k < 4; ++k) {
            const float4 Bv = *(const float4*)&sB[i][k * 4];
#pragma unroll
            for (int j = 0; j < 4; ++j) {
                const int n = k * 4 + j;
                const float e = __expf(d * A[n]);
                h[n] = e * h[n] + dx * (&Bv.x)[j];
            }
        }
        dp += DI; xcp += DI;
        d = dn; xv = xn;
    }

    u16* hp = hfin + ((size_t)(b * NC + c) * DI + ch) * 16;
#pragma unroll
    for (int k = 0; k < 4; ++k) {
        ushort4 o;
        o.x = f2bf(h[4*k]); o.y = f2bf(h[4*k+1]);
        o.z = f2bf(h[4*k+2]); o.w = f2bf(h[4*k+3]);
        *(ushort4*)(hp + 4 * k) = o;
    }
    Ssum[(size_t)(b * NC + c) * DI + ch] = S;
}

// combine: h0[c] = hfin[c-1] + exp(A*S[c-1])*h0[c-1]. thread=(b,ch,n).
__global__ __launch_bounds__(256)
void scan_combine(const u16* __restrict__ hfin, const float* __restrict__ Ssum,
                  const float* __restrict__ A_log, u16* __restrict__ h0buf)
{
    const int idx  = blockIdx.x * 256 + threadIdx.x;   // [0, B*DI*16)
    const int b    = idx >> 15;                         // DI*16 = 32768
    const int base = idx & 32767;                       // ch*16 + n
    const int ch   = base >> 4;
    const float A  = -__expf(A_log[base]);

    const u16* hp  = hfin  + (size_t)b * NC * 32768 + base;
    const float* Sp = Ssum + (size_t)b * NC * DI + ch;
    u16* op        = h0buf + (size_t)b * NC * 32768 + base;

    float h0 = 0.f;
#pragma unroll 4
    for (int c = 0; c < NC; ++c) {
        *op = f2bf(h0);
        h0 = bf2f(*hp) + __expf(A * (*Sp)) * h0;
        hp += 32768; Sp += DI; op += 32768;
    }
}

__global__ __launch_bounds__(256)
void scan_pass2(const u16* __restrict__ dlt16, const float* __restrict__ xdbl,
                const u16* __restrict__ xc, const u16* __restrict__ sres,
                const float* __restrict__ A_log, const float* __restrict__ Dp,
                const u16* __restrict__ h0buf, u16* __restrict__ yfin)
{
    const int tid = threadIdx.x;
    const int ch  = blockIdx.x * 256 + tid;
    const int b   = blockIdx.y / NC;
    const int c   = blockIdx.y % NC;
    const int t0  = b * L_SZ + c * CLEN;

    __shared__ float sB[CLEN][16], sC[CLEN][16];
    {   // CLEN*16 == 256
        const int i = tid >> 4, nn = tid & 15;
        sB[i][nn] = xdbl[(size_t)(t0 + i) * XDS + 64 + nn];
        sC[i][nn] = xdbl[(size_t)(t0 + i) * XDS + 80 + nn];
    }

    float A[16];
    {
        const float4* Ar = (const float4*)(A_log + (size_t)ch * 16);
#pragma unroll
        for (int k = 0; k < 4; ++k) {
            const float4 v = Ar[k];
            A[4*k+0] = -__expf(v.x); A[4*k+1] = -__expf(v.y);
            A[4*k+2] = -__expf(v.z); A[4*k+3] = -__expf(v.w);
        }
    }
    const float Dval = Dp[ch];

    float h[16];
    {
        const u16* hp = h0buf + (size_t)(b * NC + c) * 32768 + (size_t)ch * 16;
#pragma unroll
        for (int k = 0; k < 4; ++k) {
            const ushort4 q = *(const ushort4*)(hp + 4 * k);
            h[4*k+0] = bf2f(q.x); h[4*k+1] = bf2f(q.y);
            h[4*k+2] = bf2f(q.z); h[4*k+3] = bf2f(q.w);
        }
    }
    __syncthreads();

    const u16* dp  = dlt16 + (size_t)t0 * DI + ch;
    const u16* xcp = xc    + (size_t)t0 * DI + ch;
    const u16* srp = sres  + (size_t)t0 * DI + ch;
    u16* yp        = yfin  + (size_t)t0 * DI + ch;
    float d  = bf2f(*dp);
    float xv = bf2f(*xcp);
    float rv = bf2f(*srp);

    for (int i = 0; i < CLEN; ++i) {
        const float dn = bf2f(dp[DI]);     // unconditional prefetch
        const float xn = bf2f(xcp[DI]);
        const float rn = bf2f(srp[DI]);
        const float dx = d * xv;
        float acc0 = 0.f, acc1 = 0.f, acc2 = 0.f, acc3 = 0.f;
#pragma unroll
        for (int k = 0; k < 4; ++k) {
            const float4 Bv = *(const float4*)&sB[i][k * 4];
            const float4 Cv = *(const float4*)&sC[i][k * 4];
#pragma unroll
            for (int j = 0; j < 4; ++j) {
                const int n = k * 4 + j;
                const float e = __expf(d * A[n]);
                h[n] = e * h[n] + dx * (&Bv.x)[j];
                const float t = h[n] * (&Cv.x)[j];
                if (j == 0) acc0 += t; else if (j == 1) acc1 += t;
                else if (j == 2) acc2 += t; else acc3 += t;
            }
        }
        const float p = (acc0 + acc1) + (acc2 + acc3);
        const float y = (p + Dval * xv) * rv;
        *yp = f2bf(y);
        dp += DI; xcp += DI; srp += DI; yp += DI;
        d = dn; xv = xn; rv = rn;
    }
}

// ---------------------------------------------------------------------------
extern "C" void kernel_launch(void* const* d_in, const int* in_sizes, int n_in,
                              void* d_out, int out_size, void* d_ws, size_t ws_size,
                              hipStream_t stream)
{
    const float* x      = (const float*)d_in[0];
    const float* W_in   = (const float*)d_in[1];
    const float* conv_w = (const float*)d_in[2];
    const float* conv_b = (const float*)d_in[3];
    const float* W_x    = (const float*)d_in[4];
    const float* W_dt   = (const float*)d_in[5];
    const float* b_dt   = (const float*)d_in[6];
    const float* A_log  = (const float*)d_in[7];
    const float* D_par  = (const float*)d_in[8];
    const float* W_out  = (const float*)d_in[9];
    float* out = (float*)d_out;

    char* ws = (char*)d_ws;
    size_t off = 0;
    u16* xb    = (u16*)(ws + off); off += (size_t)TOK * DM * 2;        //  8.4 MB
    u16* Winb  = (u16*)(ws + off); off += (size_t)(2 * DI) * DM * 2;   //  8.4 MB
    u16* Woutb = (u16*)(ws + off); off += (size_t)DM * DI * 2;         //  4.2 MB
    u16* Wxb   = (u16*)(ws + off); off += (size_t)XDS * DI * 2;        //  0.5 MB
    u16* Wdtb  = (u16*)(ws + off); off += (size_t)DI * RNK * 2;        //  0.3 MB
    u16* dltB  = (u16*)(ws + off); off += (size_t)TOK * RNK * 2;       //  0.5 MB
    u16* xm    = (u16*)(ws + off); off += (size_t)TOK * DI * 2;        // 16.8 MB
    u16* xc    = (u16*)(ws + off); off += (size_t)TOK * DI * 2;        // 16.8 MB
    u16* sres  = (u16*)(ws + off); off += (size_t)TOK * DI * 2;        // 16.8 MB
    float* xdblP = (float*)(ws + off); off += (size_t)TOK * XDS * 4;   //  2.1 MB
    u16* dlt16   = (u16*)(ws + off);   off += (size_t)TOK * DI * 2;    // 16.8 MB
    u16* hfin    = (u16*)(ws + off);   off += (size_t)NC * B_SZ * DI * NST * 2; // 16.8 MB
    u16* h0buf   = (u16*)(ws + off);   off += (size_t)NC * B_SZ * DI * NST * 2; // 16.8 MB
    float* Ssum  = (float*)(ws + off); off += (size_t)NC * B_SZ * DI * 4;       //  2.1 MB
    u16* yfin = xm;              // xm dead after conv — reuse
    float* part = (float*)hfin;  // hfin (16.8 MB) dead until scan_pass1 — reuse

    // 0. convert all GEMM operands f32 -> bf16 (single launch)
    cvt_all<<<(Q_WDT + 255) / 256, 256, 0, stream>>>(
        (const float4*)x, (const float4*)W_in, (const float4*)W_out,
        (const float4*)W_x, (const float4*)W_dt,
        (ushort4*)xb, (ushort4*)Winb, (ushort4*)Woutb,
        (ushort4*)Wxb, (ushort4*)Wdtb);

    // 1. in_proj
    gemm_bt<1><<<dim3(TOK / 128, (2 * DI) / 128), 256, 0, stream>>>(
        xb, Winb, DM, 2 * DI, xm, sres, nullptr, nullptr);

    // 2. causal depthwise conv + silu (x4 vectorized)
    conv_silu_kernel<<<(TOK * DI / 4) / 256, 256, 0, stream>>>(xm, conv_w, conv_b, xc);

    // 3. x_dbl = xc @ W_x^T  (MFMA, K-split 8, then reduce + emit dltB bf16)
    gemm_xdbl<<<dim3(TOK / 128, KSPL), 256, 0, stream>>>(xc, Wxb, part);
    reduce_part<<<(TOK * XDS / 4) / 256, 256, 0, stream>>>(
        (const float4*)part, (float4*)xdblP, dltB);

    // 4. delta = softplus(dltB @ W_dt^T + b_dt)  — MFMA K=64, bf16 output
    gemm_bt<2><<<dim3(TOK / 128, DI / 128), 256, 0, stream>>>(
        dltB, Wdtb, RNK, DI, dlt16, nullptr, nullptr, b_dt);

    // 5. chunked selective scan (NC=128)
    scan_pass1<<<dim3(DI / 256, B_SZ * NC), 256, 0, stream>>>(
        dlt16, xdblP, xc, A_log, hfin, Ssum);
    scan_combine<<<(B_SZ * DI * NST) / 256, 256, 0, stream>>>(
        hfin, Ssum, A_log, h0buf);
    scan_pass2<<<dim3(DI / 256, B_SZ * NC), 256, 0, stream>>>(
        dlt16, xdblP, xc, sres, A_log, D_par, h0buf, yfin);

    // 6. out = yfin @ W_out^T (f32 store)
    gemm_bt<0><<<dim3(TOK / 128, DM / 128), 256, 0, stream>>>(
        yfin, Woutb, DI, DM, nullptr, nullptr, out, nullptr);
}

// Round 11
// 326.814 us; speedup vs baseline: 1.0884x; 1.0884x over previous
//
#include <hip/hip_runtime.h>

typedef unsigned short u16;
typedef __attribute__((ext_vector_type(8))) short bf16x8;
typedef __attribute__((ext_vector_type(4))) float f32x4;

#define B_SZ   2
#define L_SZ   2048
#define DM     1024
#define DI     2048
#define NST    16
#define RNK    64
#define TOK    (B_SZ * L_SZ)   // 4096
#define NC     128             // scan chunks (8 blocks/CU)
#define CLEN   (L_SZ / NC)     // 16 steps per chunk
#define XDS    128             // x_dbl row stride (padded from 96)
#define KSPL   8               // K-split for xdbl gemm

__device__ __forceinline__ float bf2f(u16 u) {
    return __uint_as_float(((unsigned int)u) << 16);
}
__device__ __forceinline__ u16 f2bf(float f) {
    unsigned int x = __float_as_uint(f);
    x += 0x7fffu + ((x >> 16) & 1u);   // RNE
    return (u16)(x >> 16);
}
__device__ __forceinline__ float silu(float v) {
    return v / (1.f + __expf(-v));
}
__device__ __forceinline__ float softplus_f(float v) {
    return (v > 20.f) ? v : log1pf(__expf(v));
}
// 16-byte async global->LDS (gfx950). LDS dest = wave-uniform base + lane*16.
__device__ __forceinline__ void gload16(const u16* g, u16* l) {
    __builtin_amdgcn_global_load_lds(
        (const __attribute__((address_space(1))) void*)g,
        (__attribute__((address_space(3))) void*)l, 16, 0, 0);
}
__device__ __forceinline__ ushort4 cvt4(const float4 v) {
    ushort4 o;
    o.x = f2bf(v.x); o.y = f2bf(v.y); o.z = f2bf(v.z); o.w = f2bf(v.w);
    return o;
}

// ---------------------------------------------------------------------------
// Fused f32 -> bf16 conversion of all 5 GEMM operands (one launch).
// ---------------------------------------------------------------------------
#define Q_XB   1048576                    // TOK*DM/4
#define Q_WIN  (Q_XB + 1048576)           // + 2*DI*DM/4
#define Q_WOUT (Q_WIN + 524288)           // + DM*DI/4
#define Q_WX   (Q_WOUT + 65536)           // + XDS*DI/4 (padded)
#define Q_WDT  (Q_WX + 32768)             // + DI*RNK/4
__global__ __launch_bounds__(256)
void cvt_all(const float4* __restrict__ x,  const float4* __restrict__ Wi,
             const float4* __restrict__ Wo, const float4* __restrict__ Wx,
             const float4* __restrict__ Wd,
             ushort4* __restrict__ xb,  ushort4* __restrict__ Wib,
             ushort4* __restrict__ Wob, ushort4* __restrict__ Wxb,
             ushort4* __restrict__ Wdb)
{
    const int i = blockIdx.x * 256 + threadIdx.x;
    if (i < Q_XB) {
        xb[i] = cvt4(x[i]);
    } else if (i < Q_WIN) {
        const int j = i - Q_XB;  Wib[j] = cvt4(Wi[j]);
    } else if (i < Q_WOUT) {
        const int j = i - Q_WIN; Wob[j] = cvt4(Wo[j]);
    } else if (i < Q_WX) {
        const int j = i - Q_WOUT;
        const int row = (j * 4) >> 11;
        if (row < 96) Wxb[j] = cvt4(Wx[j]);
        else          Wxb[j] = (ushort4){0, 0, 0, 0};
    } else if (i < Q_WDT) {
        const int j = i - Q_WX;  Wdb[j] = cvt4(Wd[j]);
    }
}

// ---------------------------------------------------------------------------
// GEMM 128x128 tile (in_proj). Swapped-MFMA epilogue, gload16 staging.
// EPI==1: in_proj split (out0 = x_m bf16, out1 = silu(res) bf16)
// ---------------------------------------------------------------------------
__global__ __launch_bounds__(256, 2)
void gemm_in(const u16* __restrict__ A, const u16* __restrict__ B,
             u16* __restrict__ out0, u16* __restrict__ out1)
{
    const int K = DM, N = 2 * DI;
    __shared__ u16 sA[128 * 32];
    __shared__ u16 sB[128 * 32];

    const int tid  = threadIdx.x;
    const int rowBase = blockIdx.x << 7;
    const int colBase = blockIdx.y << 7;
    const int wave = tid >> 6, lane = tid & 63;
    const int wm = (wave >> 1) << 6;
    const int wn = (wave & 1) << 6;
    const int lrow = lane & 15, quad = lane >> 4;

    const int sr  = tid >> 2;
    const int skc = tid & 3;
    const u16* Ap = A + (size_t)(rowBase + sr) * K + skc * 8;
    const u16* Bp = B + (size_t)(colBase + sr) * K + skc * 8;
    const size_t rowJump = (size_t)64 * K;
    u16* lA0 = &sA[tid * 8];
    u16* lA1 = &sA[64 * 32 + tid * 8];
    u16* lB0 = &sB[tid * 8];
    u16* lB1 = &sB[64 * 32 + tid * 8];

    f32x4 acc[4][4];
#pragma unroll
    for (int i = 0; i < 4; ++i)
#pragma unroll
        for (int j = 0; j < 4; ++j) acc[i][j] = (f32x4){0.f, 0.f, 0.f, 0.f};

    const int KT = K >> 5;
    for (int kt = 0; kt < KT; ++kt) {
        const int ko = kt * 32;
        gload16(Ap + ko, lA0);
        gload16(Ap + ko + rowJump, lA1);
        gload16(Bp + ko, lB0);
        gload16(Bp + ko + rowJump, lB1);
        __syncthreads();

        bf16x8 af[4], bfr[4];
#pragma unroll
        for (int i = 0; i < 4; ++i)
            af[i] = *(const bf16x8*)&sA[(wm + i * 16 + lrow) * 32 + quad * 8];
#pragma unroll
        for (int j = 0; j < 4; ++j)
            bfr[j] = *(const bf16x8*)&sB[(wn + j * 16 + lrow) * 32 + quad * 8];

#pragma unroll
        for (int i = 0; i < 4; ++i)
#pragma unroll
            for (int j = 0; j < 4; ++j)
                acc[i][j] = __builtin_amdgcn_mfma_f32_16x16x32_bf16(
                    bfr[j], af[i], acc[i][j], 0, 0, 0);   // swapped: C^T frags
        __syncthreads();
    }

#pragma unroll
    for (int i = 0; i < 4; ++i) {
        const int token = rowBase + wm + i * 16 + lrow;
#pragma unroll
        for (int j = 0; j < 4; ++j) {
            const int ch = colBase + wn + j * 16 + quad * 4;
            const f32x4 v = acc[i][j];
            if (ch < DI) {
                ushort4 o;
                o.x = f2bf(v[0]); o.y = f2bf(v[1]);
                o.z = f2bf(v[2]); o.w = f2bf(v[3]);
                *(ushort4*)&out0[(size_t)token * DI + ch] = o;
            } else {
                ushort4 o;
                o.x = f2bf(silu(v[0])); o.y = f2bf(silu(v[1]));
                o.z = f2bf(silu(v[2])); o.w = f2bf(silu(v[3]));
                *(ushort4*)&out1[(size_t)token * DI + (ch - DI)] = o;
            }
        }
    }
}

// ---------------------------------------------------------------------------
// GEMM 64x128 tile — for occupancy-starved GEMMs (out_proj, delta).
// 2x2 waves of 32x64; acc[2][4]; A-tile 64 rows (half staging); 12 KB LDS.
// EPI==0: float4 -> outF ; EPI==2: softplus+bias -> bf16 out0
// ---------------------------------------------------------------------------
template<int EPI>
__global__ __launch_bounds__(256, 2)
void gemm_mt64(const u16* __restrict__ A, const u16* __restrict__ B,
               const int K, const int N,
               u16* __restrict__ out0, float* __restrict__ outF,
               const float* __restrict__ bias)
{
    __shared__ u16 sA[64 * 32];
    __shared__ u16 sB[128 * 32];

    const int tid  = threadIdx.x;
    const int rowBase = blockIdx.x << 6;
    const int colBase = blockIdx.y << 7;
    const int wave = tid >> 6, lane = tid & 63;
    const int wm = (wave >> 1) << 5;          // 0 / 32
    const int wn = (wave & 1) << 6;           // 0 / 64
    const int lrow = lane & 15, quad = lane >> 4;

    const int sr  = tid >> 2;
    const int skc = tid & 3;
    const u16* Ap = A + (size_t)(rowBase + sr) * K + skc * 8;
    const u16* Bp = B + (size_t)(colBase + sr) * K + skc * 8;
    const size_t rowJump = (size_t)64 * K;
    u16* lA0 = &sA[tid * 8];
    u16* lB0 = &sB[tid * 8];
    u16* lB1 = &sB[64 * 32 + tid * 8];

    f32x4 acc[2][4];
#pragma unroll
    for (int i = 0; i < 2; ++i)
#pragma unroll
        for (int j = 0; j < 4; ++j) acc[i][j] = (f32x4){0.f, 0.f, 0.f, 0.f};

    const int KT = K >> 5;
    for (int kt = 0; kt < KT; ++kt) {
        const int ko = kt * 32;
        gload16(Ap + ko, lA0);
        gload16(Bp + ko, lB0);
        gload16(Bp + ko + rowJump, lB1);
        __syncthreads();

        bf16x8 af[2], bfr[4];
#pragma unroll
        for (int i = 0; i < 2; ++i)
            af[i] = *(const bf16x8*)&sA[(wm + i * 16 + lrow) * 32 + quad * 8];
#pragma unroll
        for (int j = 0; j < 4; ++j)
            bfr[j] = *(const bf16x8*)&sB[(wn + j * 16 + lrow) * 32 + quad * 8];

#pragma unroll
        for (int i = 0; i < 2; ++i)
#pragma unroll
            for (int j = 0; j < 4; ++j)
                acc[i][j] = __builtin_amdgcn_mfma_f32_16x16x32_bf16(
                    bfr[j], af[i], acc[i][j], 0, 0, 0);
        __syncthreads();
    }

#pragma unroll
    for (int i = 0; i < 2; ++i) {
        const int token = rowBase + wm + i * 16 + lrow;
#pragma unroll
        for (int j = 0; j < 4; ++j) {
            const int ch = colBase + wn + j * 16 + quad * 4;
            const f32x4 v = acc[i][j];
            if (EPI == 0) {
                *(float4*)&outF[(size_t)token * N + ch] =
                    (float4){v[0], v[1], v[2], v[3]};
            } else {
                const float4 bb = *(const float4*)&bias[ch];
                ushort4 o;
                o.x = f2bf(softplus_f(v[0] + bb.x));
                o.y = f2bf(softplus_f(v[1] + bb.y));
                o.z = f2bf(softplus_f(v[2] + bb.z));
                o.w = f2bf(softplus_f(v[3] + bb.w));
                *(ushort4*)&out0[(size_t)token * N + ch] = o;
            }
        }
    }
}

// ---------------------------------------------------------------------------
// xdbl GEMM: part[ks][128 tokens][128] = xc_tile @ WxP^T over K-slice ks*256.
// ---------------------------------------------------------------------------
__global__ __launch_bounds__(256, 2)
void gemm_xdbl(const u16* __restrict__ A, const u16* __restrict__ B,
               float* __restrict__ part)
{
    __shared__ u16 sA[128 * 32];
    __shared__ u16 sB[128 * 32];

    const int tid  = threadIdx.x;
    const int rowBase = blockIdx.x << 7;
    const int ks   = blockIdx.y;
    const int k0   = ks * (DI / KSPL);
    const int wave = tid >> 6, lane = tid & 63;
    const int wm = (wave >> 1) << 6;
    const int wn = (wave & 1) << 6;
    const int lrow = lane & 15, quad = lane >> 4;

    const int sr  = tid >> 2;
    const int skc = tid & 3;
    const u16* Ap = A + (size_t)(rowBase + sr) * DI + k0 + skc * 8;
    const u16* Bp = B + (size_t)sr * DI + k0 + skc * 8;
    const size_t rowJump = (size_t)64 * DI;
    u16* lA0 = &sA[tid * 8];
    u16* lA1 = &sA[64 * 32 + tid * 8];
    u16* lB0 = &sB[tid * 8];
    u16* lB1 = &sB[64 * 32 + tid * 8];

    f32x4 acc[4][4];
#pragma unroll
    for (int i = 0; i < 4; ++i)
#pragma unroll
        for (int j = 0; j < 4; ++j) acc[i][j] = (f32x4){0.f, 0.f, 0.f, 0.f};

    const int KT = (DI / KSPL) >> 5;            // 8
    for (int kt = 0; kt < KT; ++kt) {
        const int ko = kt * 32;
        gload16(Ap + ko, lA0);
        gload16(Ap + ko + rowJump, lA1);
        gload16(Bp + ko, lB0);
        gload16(Bp + ko + rowJump, lB1);
        __syncthreads();

        bf16x8 af[4], bfr[4];
#pragma unroll
        for (int i = 0; i < 4; ++i)
            af[i] = *(const bf16x8*)&sA[(wm + i * 16 + lrow) * 32 + quad * 8];
#pragma unroll
        for (int j = 0; j < 4; ++j)
            bfr[j] = *(const bf16x8*)&sB[(wn + j * 16 + lrow) * 32 + quad * 8];

#pragma unroll
        for (int i = 0; i < 4; ++i)
#pragma unroll
            for (int j = 0; j < 4; ++j)
                acc[i][j] = __builtin_amdgcn_mfma_f32_16x16x32_bf16(
                    bfr[j], af[i], acc[i][j], 0, 0, 0);
        __syncthreads();
    }

    float* base = part + (size_t)ks * TOK * XDS;
#pragma unroll
    for (int i = 0; i < 4; ++i) {
        const int token = rowBase + wm + i * 16 + lrow;
#pragma unroll
        for (int j = 0; j < 4; ++j) {
            const int ch = wn + j * 16 + quad * 4;
            const f32x4 v = acc[i][j];
            *(float4*)&base[(size_t)token * XDS + ch] =
                (float4){v[0], v[1], v[2], v[3]};
        }
    }
}

// sum the 8 K-slice partials -> xdblP [TOK x 128] f32; also emit dltB
__global__ __launch_bounds__(256)
void reduce_part(const float4* __restrict__ part, float4* __restrict__ xdbl,
                 u16* __restrict__ dltB)
{
    const int i = blockIdx.x * 256 + threadIdx.x;   // [0, TOK*XDS/4)
    const int n4 = TOK * XDS / 4;
    float4 s = part[i];
#pragma unroll
    for (int ks = 1; ks < KSPL; ++ks) {
        const float4 v = part[(size_t)ks * n4 + i];
        s.x += v.x; s.y += v.y; s.z += v.z; s.w += v.w;
    }
    xdbl[i] = s;
    const int col4 = (i & (XDS / 4 - 1)) * 4;
    if (col4 < RNK) {
        const int row = i >> 5;                      // XDS/4 = 32
        *(ushort4*)(dltB + (size_t)row * RNK + col4) = cvt4(s);
    }
}

// ---------------------------------------------------------------------------
// causal depthwise conv (K=4) + silu — vectorized x4 channels/thread
// ---------------------------------------------------------------------------
__global__ __launch_bounds__(256)
void conv_silu_kernel(const u16* __restrict__ xm, const float* __restrict__ cw,
                      const float* __restrict__ cb, u16* __restrict__ xc)
{
    const int idx = blockIdx.x * 256 + threadIdx.x;   // [0, TOK*DI/4)
    const int ch  = (idx & (DI / 4 - 1)) * 4;
    const int t   = idx >> 9;                          // DI/4 = 512
    const int l   = t & (L_SZ - 1);

    const float4 w0 = ((const float4*)cw)[ch];
    const float4 w1 = ((const float4*)cw)[ch + 1];
    const float4 w2 = ((const float4*)cw)[ch + 2];
    const float4 w3 = ((const float4*)cw)[ch + 3];
    const float4 bb = *(const float4*)(cb + ch);
    float a0 = bb.x, a1 = bb.y, a2 = bb.z, a3 = bb.w;

    const u16* base = xm + (size_t)t * DI + ch;
    if (l >= 3) {
        const ushort4 v = *(const ushort4*)(base - 3 * DI);
        a0 += w0.x * bf2f(v.x); a1 += w1.x * bf2f(v.y);
        a2 += w2.x * bf2f(v.z); a3 += w3.x * bf2f(v.w);
    }
    if (l >= 2) {
        const ushort4 v = *(const ushort4*)(base - 2 * DI);
        a0 += w0.y * bf2f(v.x); a1 += w1.y * bf2f(v.y);
        a2 += w2.y * bf2f(v.z); a3 += w3.y * bf2f(v.w);
    }
    if (l >= 1) {
        const ushort4 v = *(const ushort4*)(base - DI);
        a0 += w0.z * bf2f(v.x); a1 += w1.z * bf2f(v.y);
        a2 += w2.z * bf2f(v.z); a3 += w3.z * bf2f(v.w);
    }
    {
        const ushort4 v = *(const ushort4*)(base);
        a0 += w0.w * bf2f(v.x); a1 += w1.w * bf2f(v.y);
        a2 += w2.w * bf2f(v.z); a3 += w3.w * bf2f(v.w);
    }
    ushort4 o;
    o.x = f2bf(silu(a0)); o.y = f2bf(silu(a1));
    o.z = f2bf(silu(a2)); o.w = f2bf(silu(a3));
    *(ushort4*)(xc + (size_t)t * DI + ch) = o;
}

// ---------------------------------------------------------------------------
// Chunked selective scan (NC=128, CLEN=16). thread = channel; states in regs.
// ---------------------------------------------------------------------------
__global__ __launch_bounds__(256)
void scan_pass1(const u16* __restrict__ dlt16, const float* __restrict__ xdbl,
                const u16* __restrict__ xc, const float* __restrict__ A_log,
                u16* __restrict__ hfin, float* __restrict__ Ssum)
{
    const int tid = threadIdx.x;
    const int ch  = blockIdx.x * 256 + tid;
    const int b   = blockIdx.y / NC;
    const int c   = blockIdx.y % NC;
    const int t0  = b * L_SZ + c * CLEN;

    __shared__ float sB[CLEN][16];
    {   // CLEN*16 == 256
        const int i = tid >> 4, nn = tid & 15;
        sB[i][nn] = xdbl[(size_t)(t0 + i) * XDS + 64 + nn];
    }

    float A[16];
    {
        const float4* Ar = (const float4*)(A_log + (size_t)ch * 16);
#pragma unroll
        for (int k = 0; k < 4; ++k) {
            const float4 v = Ar[k];
            A[4*k+0] = -__expf(v.x); A[4*k+1] = -__expf(v.y);
            A[4*k+2] = -__expf(v.z); A[4*k+3] = -__expf(v.w);
        }
    }
    __syncthreads();

    float h[16];
#pragma unroll
    for (int n = 0; n < 16; ++n) h[n] = 0.f;
    float S = 0.f;

    const u16* dp  = dlt16 + (size_t)t0 * DI + ch;
    const u16* xcp = xc    + (size_t)t0 * DI + ch;
    float d  = bf2f(*dp);
    float xv = bf2f(*xcp);

    for (int i = 0; i < CLEN; ++i) {
        const float dn = bf2f(dp[DI]);     // unconditional prefetch
        const float xn = bf2f(xcp[DI]);
        const float dx = d * xv;
        S += d;
#pragma unroll
        for (int k = 0; k < 4; ++k) {
            const float4 Bv = *(const float4*)&sB[i][k * 4];
#pragma unroll
            for (int j = 0; j < 4; ++j) {
                const int n = k * 4 + j;
                const float e = __expf(d * A[n]);
                h[n] = e * h[n] + dx * (&Bv.x)[j];
            }
        }
        dp += DI; xcp += DI;
        d = dn; xv = xn;
    }

    u16* hp = hfin + ((size_t)(b * NC + c) * DI + ch) * 16;
#pragma unroll
    for (int k = 0; k < 4; ++k) {
        ushort4 o;
        o.x = f2bf(h[4*k]); o.y = f2bf(h[4*k+1]);
        o.z = f2bf(h[4*k+2]); o.w = f2bf(h[4*k+3]);
        *(ushort4*)(hp + 4 * k) = o;
    }
    Ssum[(size_t)(b * NC + c) * DI + ch] = S;
}

// combine: h0[c] = hfin[c-1] + exp(A*S[c-1])*h0[c-1]. thread=(b,ch,n).
__global__ __launch_bounds__(256)
void scan_combine(const u16* __restrict__ hfin, const float* __restrict__ Ssum,
                  const float* __restrict__ A_log, u16* __restrict__ h0buf)
{
    const int idx  = blockIdx.x * 256 + threadIdx.x;   // [0, B*DI*16)
    const int b    = idx >> 15;                         // DI*16 = 32768
    const int base = idx & 32767;                       // ch*16 + n
    const int ch   = base >> 4;
    const float A  = -__expf(A_log[base]);

    const u16* hp  = hfin  + (size_t)b * NC * 32768 + base;
    const float* Sp = Ssum + (size_t)b * NC * DI + ch;
    u16* op        = h0buf + (size_t)b * NC * 32768 + base;

    float h0 = 0.f;
#pragma unroll 4
    for (int c = 0; c < NC; ++c) {
        *op = f2bf(h0);
        h0 = bf2f(*hp) + __expf(A * (*Sp)) * h0;
        hp += 32768; Sp += DI; op += 32768;
    }
}

__global__ __launch_bounds__(256)
void scan_pass2(const u16* __restrict__ dlt16, const float* __restrict__ xdbl,
                const u16* __restrict__ xc, const u16* __restrict__ sres,
                const float* __restrict__ A_log, const float* __restrict__ Dp,
                const u16* __restrict__ h0buf, u16* __restrict__ yfin)
{
    const int tid = threadIdx.x;
    const int ch  = blockIdx.x * 256 + tid;
    const int b   = blockIdx.y / NC;
    const int c   = blockIdx.y % NC;
    const int t0  = b * L_SZ + c * CLEN;

    __shared__ float sB[CLEN][16], sC[CLEN][16];
    {   // CLEN*16 == 256
        const int i = tid >> 4, nn = tid & 15;
        sB[i][nn] = xdbl[(size_t)(t0 + i) * XDS + 64 + nn];
        sC[i][nn] = xdbl[(size_t)(t0 + i) * XDS + 80 + nn];
    }

    float A[16];
    {
        const float4* Ar = (const float4*)(A_log + (size_t)ch * 16);
#pragma unroll
        for (int k = 0; k < 4; ++k) {
            const float4 v = Ar[k];
            A[4*k+0] = -__expf(v.x); A[4*k+1] = -__expf(v.y);
            A[4*k+2] = -__expf(v.z); A[4*k+3] = -__expf(v.w);
        }
    }
    const float Dval = Dp[ch];

    float h[16];
    {
        const u16* hp = h0buf + (size_t)(b * NC + c) * 32768 + (size_t)ch * 16;
#pragma unroll
        for (int k = 0; k < 4; ++k) {
            const ushort4 q = *(const ushort4*)(hp + 4 * k);
            h[4*k+0] = bf2f(q.x); h[4*k+1] = bf2f(q.y);
            h[4*k+2] = bf2f(q.z); h[4*k+3] = bf2f(q.w);
        }
    }
    __syncthreads();

    const u16* dp  = dlt16 + (size_t)t0 * DI + ch;
    const u16* xcp = xc    + (size_t)t0 * DI + ch;
    const u16* srp = sres  + (size_t)t0 * DI + ch;
    u16* yp        = yfin  + (size_t)t0 * DI + ch;
    float d  = bf2f(*dp);
    float xv = bf2f(*xcp);
    float rv = bf2f(*srp);

    for (int i = 0; i < CLEN; ++i) {
        const float dn = bf2f(dp[DI]);     // unconditional prefetch
        const float xn = bf2f(xcp[DI]);
        const float rn = bf2f(srp[DI]);
        const float dx = d * xv;
        float acc0 = 0.f, acc1 = 0.f, acc2 = 0.f, acc3 = 0.f;
#pragma unroll
        for (int k = 0; k < 4; ++k) {
            const float4 Bv = *(const float4*)&sB[i][k * 4];
            const float4 Cv = *(const float4*)&sC[i][k * 4];
#pragma unroll
            for (int j = 0; j < 4; ++j) {
                const int n = k * 4 + j;
                const float e = __expf(d * A[n]);
                h[n] = e * h[n] + dx * (&Bv.x)[j];
                const float t = h[n] * (&Cv.x)[j];
                if (j == 0) acc0 += t; else if (j == 1) acc1 += t;
                else if (j == 2) acc2 += t; else acc3 += t;
            }
        }
        const float p = (acc0 + acc1) + (acc2 + acc3);
        const float y = (p + Dval * xv) * rv;
        *yp = f2bf(y);
        dp += DI; xcp += DI; srp += DI; yp += DI;
        d = dn; xv = xn; rv = rn;
    }
}

// ---------------------------------------------------------------------------
extern "C" void kernel_launch(void* const* d_in, const int* in_sizes, int n_in,
                              void* d_out, int out_size, void* d_ws, size_t ws_size,
                              hipStream_t stream)
{
    const float* x      = (const float*)d_in[0];
    const float* W_in   = (const float*)d_in[1];
    const float* conv_w = (const float*)d_in[2];
    const float* conv_b = (const float*)d_in[3];
    const float* W_x    = (const float*)d_in[4];
    const float* W_dt   = (const float*)d_in[5];
    const float* b_dt   = (const float*)d_in[6];
    const float* A_log  = (const float*)d_in[7];
    const float* D_par  = (const float*)d_in[8];
    const float* W_out  = (const float*)d_in[9];
    float* out = (float*)d_out;

    char* ws = (char*)d_ws;
    size_t off = 0;
    u16* xb    = (u16*)(ws + off); off += (size_t)TOK * DM * 2;        //  8.4 MB
    u16* Winb  = (u16*)(ws + off); off += (size_t)(2 * DI) * DM * 2;   //  8.4 MB
    u16* Woutb = (u16*)(ws + off); off += (size_t)DM * DI * 2;         //  4.2 MB
    u16* Wxb   = (u16*)(ws + off); off += (size_t)XDS * DI * 2;        //  0.5 MB
    u16* Wdtb  = (u16*)(ws + off); off += (size_t)DI * RNK * 2;        //  0.3 MB
    u16* dltB  = (u16*)(ws + off); off += (size_t)TOK * RNK * 2;       //  0.5 MB
    u16* xm    = (u16*)(ws + off); off += (size_t)TOK * DI * 2;        // 16.8 MB
    u16* xc    = (u16*)(ws + off); off += (size_t)TOK * DI * 2;        // 16.8 MB
    u16* sres  = (u16*)(ws + off); off += (size_t)TOK * DI * 2;        // 16.8 MB
    float* xdblP = (float*)(ws + off); off += (size_t)TOK * XDS * 4;   //  2.1 MB
    u16* dlt16   = (u16*)(ws + off);   off += (size_t)TOK * DI * 2;    // 16.8 MB
    u16* hfin    = (u16*)(ws + off);   off += (size_t)NC * B_SZ * DI * NST * 2; // 16.8 MB
    u16* h0buf   = (u16*)(ws + off);   off += (size_t)NC * B_SZ * DI * NST * 2; // 16.8 MB
    float* Ssum  = (float*)(ws + off); off += (size_t)NC * B_SZ * DI * 4;       //  2.1 MB
    u16* yfin = xm;              // xm dead after conv — reuse
    float* part = (float*)hfin;  // hfin (16.8 MB) dead until scan_pass1 — reuse

    // 0. convert all GEMM operands f32 -> bf16 (single launch)
    cvt_all<<<(Q_WDT + 255) / 256, 256, 0, stream>>>(
        (const float4*)x, (const float4*)W_in, (const float4*)W_out,
        (const float4*)W_x, (const float4*)W_dt,
        (ushort4*)xb, (ushort4*)Winb, (ushort4*)Woutb,
        (ushort4*)Wxb, (ushort4*)Wdtb);

    // 1. in_proj (128x128 tile, 1024 blocks)
    gemm_in<<<dim3(TOK / 128, (2 * DI) / 128), 256, 0, stream>>>(
        xb, Winb, xm, sres);

    // 2. causal depthwise conv + silu (x4 vectorized)
    conv_silu_kernel<<<(TOK * DI / 4) / 256, 256, 0, stream>>>(xm, conv_w, conv_b, xc);

    // 3. x_dbl = xc @ W_x^T  (MFMA, K-split 8, then reduce + emit dltB bf16)
    gemm_xdbl<<<dim3(TOK / 128, KSPL), 256, 0, stream>>>(xc, Wxb, part);
    reduce_part<<<(TOK * XDS / 4) / 256, 256, 0, stream>>>(
        (const float4*)part, (float4*)xdblP, dltB);

    // 4. delta = softplus(dltB @ W_dt^T + b_dt) — 64-row tiles, 1024 blocks
    gemm_mt64<2><<<dim3(TOK / 64, DI / 128), 256, 0, stream>>>(
        dltB, Wdtb, RNK, DI, dlt16, nullptr, b_dt);

    // 5. chunked selective scan (NC=128)
    scan_pass1<<<dim3(DI / 256, B_SZ * NC), 256, 0, stream>>>(
        dlt16, xdblP, xc, A_log, hfin, Ssum);
    scan_combine<<<(B_SZ * DI * NST) / 256, 256, 0, stream>>>(
        hfin, Ssum, A_log, h0buf);
    scan_pass2<<<dim3(DI / 256, B_SZ * NC), 256, 0, stream>>>(
        dlt16, xdblP, xc, sres, A_log, D_par, h0buf, yfin);

    // 6. out = yfin @ W_out^T — 64-row tiles, 512 blocks (was 256 = 1/CU)
    gemm_mt64<0><<<dim3(TOK / 64, DM / 128), 256, 0, stream>>>(
        yfin, Woutb, DI, DM, nullptr, out, nullptr);
}